// Round 1
// 189.417 us; speedup vs baseline: 1.0164x; 1.0164x over previous
//
#include <hip/hip_runtime.h>

#define NIMG 64
#define H 512
#define W 512

constexpr float THR_64  = 50.0f / 255.0f;          // level_idx=1: 64x64 details
constexpr float THR_128 = 50.0f / 2.0f / 255.0f;   // level_idx=2: 128x128
constexpr float THR_256 = 50.0f / 4.0f / 255.0f;   // level_idx=3: 256x256

// Weights folded into a single per-thread "comb" accumulator:
//   wav = a3/37748736 + a4/6291456 + a5/786432   (level means + 1/level_idx)
//   tv  = a2/16744448                            (64*511*512, both terms)
//   loss = 1.0*n2v + 0.2*wav + 0.01*tv
constexpr float SC_W1 = 0.2f  / 37748736.0f;
constexpr float SC_W2 = 0.2f  / 6291456.0f;
constexpr float SC_W3 = 0.2f  / 786432.0f;
constexpr float SC_TV = 0.01f / 16744448.0f;

__device__ __forceinline__ float wave_sum(float v) {
#pragma unroll
    for (int o = 32; o > 0; o >>= 1) v += __shfl_down(v, o, 64);
    return v;
}

__device__ __forceinline__ float clip01(float x) {
    return fminf(fmaxf(x, 0.0f), 1.0f);
}

__device__ __forceinline__ float4 clip4(float4 p) {
    p.x = clip01(p.x); p.y = clip01(p.y); p.z = clip01(p.z); p.w = clip01(p.w);
    return p;
}

// Kernel A: slab of 8 rows per block. Phase 1 issues ALL pred+mask loads and
// then ALL (predicate-gated) noisy loads before any consumption -> one memory
// latency instead of a 4-deep dependent chain. Phase 2 does TV + level-1/2
// Haar from LDS. Level-3 is fused: the slab's two LL2 rows are staged in LDS
// (1 KB) and wave 0 computes the 64 level-3 quads -> kC and the 4 MB ll2
// global round-trip are eliminated. Epilogue reduces only 3 values.
__global__ __launch_bounds__(256) void kA(const float* __restrict__ pred,
                                          const float* __restrict__ noisy,
                                          const int* __restrict__ mask,
                                          float4* __restrict__ pA) {
    __shared__ float sl[9 * 512];
    __shared__ float sll2[2][128];
    __shared__ float red[4][3];

    const int tid = threadIdx.x;
    const int lane = tid & 63;
    const int wv = tid >> 6;
    const int bid = blockIdx.x;
    const int n = bid >> 6;                  // image
    const int s = bid & 63;                  // slab (8 rows)
    const int r0 = s << 3;                   // first global row
    const size_t base = (size_t)n * (H * W) + (size_t)r0 * W;
    const size_t o0 = base + (size_t)tid * 4;   // this thread's chunk-0 offset

    // ---------- phase 1a: pred + mask for all 4 chunks, issued up front ----------
    float4 p0 = *reinterpret_cast<const float4*>(pred + o0);
    float4 p1 = *reinterpret_cast<const float4*>(pred + o0 + 1024);
    float4 p2 = *reinterpret_cast<const float4*>(pred + o0 + 2048);
    float4 p3 = *reinterpret_cast<const float4*>(pred + o0 + 3072);
    int4 m0 = *reinterpret_cast<const int4*>(mask + o0);
    int4 m1 = *reinterpret_cast<const int4*>(mask + o0 + 1024);
    int4 m2 = *reinterpret_cast<const int4*>(mask + o0 + 2048);
    int4 m3 = *reinterpret_cast<const int4*>(mask + o0 + 3072);
    // halo row (global row r0-1) -> LDS row 8 (zeros if r0 == 0)
    if (tid < 128) {
        float4 hp = make_float4(0.f, 0.f, 0.f, 0.f);
        if (r0 > 0) {
            hp = clip4(*reinterpret_cast<const float4*>(pred + base - W + (size_t)tid * 4));
        }
        *reinterpret_cast<float4*>(&sl[(8 << 9) + (tid << 2)]) = hp;
    }

    // ---------- phase 1b: hoisted sparse noisy loads (issued together) ----------
    const bool b0 = (m0.x | m0.y | m0.z | m0.w) != 0;
    const bool b1 = (m1.x | m1.y | m1.z | m1.w) != 0;
    const bool b2 = (m2.x | m2.y | m2.z | m2.w) != 0;
    const bool b3 = (m3.x | m3.y | m3.z | m3.w) != 0;
    float4 nz0 = make_float4(0.f, 0.f, 0.f, 0.f);
    float4 nz1 = nz0, nz2 = nz0, nz3 = nz0;
    if (b0) nz0 = *reinterpret_cast<const float4*>(noisy + o0);
    if (b1) nz1 = *reinterpret_cast<const float4*>(noisy + o0 + 1024);
    if (b2) nz2 = *reinterpret_cast<const float4*>(noisy + o0 + 2048);
    if (b3) nz3 = *reinterpret_cast<const float4*>(noisy + o0 + 3072);

    p0 = clip4(p0); p1 = clip4(p1); p2 = clip4(p2); p3 = clip4(p3);

    float n2v = 0.0f, msum = 0.0f;
#define ACC(P, MK, NZ)                                                           \
    {                                                                            \
        float m;                                                                 \
        m = MK.x ? 1.f : 0.f; n2v += fabsf(P.x - NZ.x) * m; msum += m;           \
        m = MK.y ? 1.f : 0.f; n2v += fabsf(P.y - NZ.y) * m; msum += m;           \
        m = MK.z ? 1.f : 0.f; n2v += fabsf(P.z - NZ.z) * m; msum += m;           \
        m = MK.w ? 1.f : 0.f; n2v += fabsf(P.w - NZ.w) * m; msum += m;           \
    }
    ACC(p0, m0, nz0)
    ACC(p1, m1, nz1)
    ACC(p2, m2, nz2)
    ACC(p3, m3, nz3)
#undef ACC
    *reinterpret_cast<float4*>(&sl[tid << 2]) = p0;
    *reinterpret_cast<float4*>(&sl[(tid + 256) << 2]) = p1;
    *reinterpret_cast<float4*>(&sl[(tid + 512) << 2]) = p2;
    *reinterpret_cast<float4*>(&sl[(tid + 768) << 2]) = p3;
    __syncthreads();

    // ---------- phase 2: TV + level-1 + level-2 Haar from LDS ----------
    const int q2 = wv >> 1;                  // row quad within slab: 0 or 1
    const int h = wv & 1;                    // col half
    const int cofs = (h << 8) + (lane << 2);
    const float* rowp = sl + (q2 << 11);     // 4*q2 rows * 512

    float4 q0 = *reinterpret_cast<const float4*>(rowp + cofs);
    float4 q1 = *reinterpret_cast<const float4*>(rowp + 512 + cofs);
    float4 qq2 = *reinterpret_cast<const float4*>(rowp + 1024 + cofs);
    float4 q3 = *reinterpret_cast<const float4*>(rowp + 1536 + cofs);
    // halo for this quad: q2==1 -> slab row 3; q2==0 -> staged halo row 8
    const float* hrow = (q2 == 1) ? (sl + 3 * 512) : (sl + 8 * 512);
    float4 hl = *reinterpret_cast<const float4*>(hrow + cofs);
    const bool has_halo = (q2 == 1) || (r0 > 0);

    float tv = 0.0f;
    // horizontal interior
    tv += fabsf(q0.y - q0.x) + fabsf(q0.z - q0.y) + fabsf(q0.w - q0.z);
    tv += fabsf(q1.y - q1.x) + fabsf(q1.z - q1.y) + fabsf(q1.w - q1.z);
    tv += fabsf(qq2.y - qq2.x) + fabsf(qq2.z - qq2.y) + fabsf(qq2.w - qq2.z);
    tv += fabsf(q3.y - q3.x) + fabsf(q3.z - q3.y) + fabsf(q3.w - q3.z);
    // horizontal boundary to next lane (shfl), seam col 255|256 from LDS
    float nx0 = __shfl_down(q0.x, 1, 64);
    float nx1 = __shfl_down(q1.x, 1, 64);
    float nx2 = __shfl_down(qq2.x, 1, 64);
    float nx3 = __shfl_down(q3.x, 1, 64);
    if (lane < 63) {
        tv += fabsf(nx0 - q0.w) + fabsf(nx1 - q1.w)
            + fabsf(nx2 - qq2.w) + fabsf(nx3 - q3.w);
    } else if (h == 0) {
        tv += fabsf(rowp[256] - q0.w) + fabsf(rowp[512 + 256] - q1.w)
            + fabsf(rowp[1024 + 256] - qq2.w) + fabsf(rowp[1536 + 256] - q3.w);
    }
    // vertical internal + halo
    tv += fabsf(q1.x - q0.x) + fabsf(q1.y - q0.y) + fabsf(q1.z - q0.z) + fabsf(q1.w - q0.w);
    tv += fabsf(qq2.x - q1.x) + fabsf(qq2.y - q1.y) + fabsf(qq2.z - q1.z) + fabsf(qq2.w - q1.w);
    tv += fabsf(q3.x - qq2.x) + fabsf(q3.y - qq2.y) + fabsf(q3.z - qq2.z) + fabsf(q3.w - qq2.w);
    if (has_halo) {
        tv += fabsf(q0.x - hl.x) + fabsf(q0.y - hl.y)
            + fabsf(q0.z - hl.z) + fabsf(q0.w - hl.w);
    }

    // level-1 Haar: 4 quads per lane
    float wav1 = 0.0f;
    float a, b, c, d, ch, cv, cd;
    a = q0.x; b = q0.y; c = q1.x; d = q1.y;
    float llA0 = (a + b + c + d) * 0.5f;
    ch = (a + b - c - d) * 0.5f; cv = (a - b + c - d) * 0.5f; cd = (a - b - c + d) * 0.5f;
    wav1 += fminf(fabsf(ch), THR_256) + fminf(fabsf(cv), THR_256) + fminf(fabsf(cd), THR_256);
    a = q0.z; b = q0.w; c = q1.z; d = q1.w;
    float llA1 = (a + b + c + d) * 0.5f;
    ch = (a + b - c - d) * 0.5f; cv = (a - b + c - d) * 0.5f; cd = (a - b - c + d) * 0.5f;
    wav1 += fminf(fabsf(ch), THR_256) + fminf(fabsf(cv), THR_256) + fminf(fabsf(cd), THR_256);
    a = qq2.x; b = qq2.y; c = q3.x; d = q3.y;
    float llB0 = (a + b + c + d) * 0.5f;
    ch = (a + b - c - d) * 0.5f; cv = (a - b + c - d) * 0.5f; cd = (a - b - c + d) * 0.5f;
    wav1 += fminf(fabsf(ch), THR_256) + fminf(fabsf(cv), THR_256) + fminf(fabsf(cd), THR_256);
    a = qq2.z; b = qq2.w; c = q3.z; d = q3.w;
    float llB1 = (a + b + c + d) * 0.5f;
    ch = (a + b - c - d) * 0.5f; cv = (a - b + c - d) * 0.5f; cd = (a - b - c + d) * 0.5f;
    wav1 += fminf(fabsf(ch), THR_256) + fminf(fabsf(cv), THR_256) + fminf(fabsf(cd), THR_256);

    // level-2 Haar: lane-local quad
    float wav2, ll2v;
    {
        a = llA0; b = llA1; c = llB0; d = llB1;
        ll2v = (a + b + c + d) * 0.5f;
        ch = (a + b - c - d) * 0.5f;
        cv = (a - b + c - d) * 0.5f;
        cd = (a - b - c + d) * 0.5f;
        wav2 = fminf(fabsf(ch), THR_128) + fminf(fabsf(cv), THR_128) + fminf(fabsf(cd), THR_128);
    }
    // Stage this slab's two LL2 rows (2 x 128) in LDS for fused level-3.
    // row = q2 (local), col = 64h + lane
    sll2[q2][(h << 6) + lane] = ll2v;

    // fold everything except n2v/msum into one pre-scaled accumulator
    float comb = wav1 * SC_W1 + wav2 * SC_W2 + tv * SC_TV;
    __syncthreads();

    // ---------- fused level-3: 64 quads, one per lane of wave 0 ----------
    if (wv == 0) {
        float2 top = *reinterpret_cast<const float2*>(&sll2[0][lane << 1]);
        float2 bot = *reinterpret_cast<const float2*>(&sll2[1][lane << 1]);
        a = top.x; b = top.y; c = bot.x; d = bot.y;
        ch = (a + b - c - d) * 0.5f;
        cv = (a - b + c - d) * 0.5f;
        cd = (a - b - c + d) * 0.5f;
        comb += (fminf(fabsf(ch), THR_64) + fminf(fabsf(cv), THR_64)
               + fminf(fabsf(cd), THR_64)) * SC_W3;
    }

    // ---------- block reduction -> plain stores ----------
    float v0 = wave_sum(n2v);
    float v1 = wave_sum(msum);
    float v2 = wave_sum(comb);
    if (lane == 0) {
        red[wv][0] = v0; red[wv][1] = v1; red[wv][2] = v2;
    }
    __syncthreads();
    if (tid == 0) {
        pA[bid] = make_float4(red[0][0] + red[1][0] + red[2][0] + red[3][0],
                              red[0][1] + red[1][1] + red[2][1] + red[3][1],
                              red[0][2] + red[1][2] + red[2][2] + red[3][2],
                              0.0f);
    }
}

// Kernel D: reduce 4096 float4 partials, compose final loss.
__global__ __launch_bounds__(256) void kD(const float4* __restrict__ pA,
                                          float* __restrict__ out) {
    __shared__ float red[4][3];
    const int tid = threadIdx.x;
    const int lane = tid & 63, wv = tid >> 6;

    float s0 = 0, s1 = 0, s2 = 0;
#pragma unroll
    for (int j = 0; j < 16; ++j) {
        float4 v = pA[tid + (j << 8)];
        s0 += v.x; s1 += v.y; s2 += v.z;
    }
    s0 = wave_sum(s0); s1 = wave_sum(s1); s2 = wave_sum(s2);
    if (lane == 0) {
        red[wv][0] = s0; red[wv][1] = s1; red[wv][2] = s2;
    }
    __syncthreads();
    if (tid == 0) {
        float a0 = red[0][0] + red[1][0] + red[2][0] + red[3][0];
        float a1 = red[0][1] + red[1][1] + red[2][1] + red[3][1];
        float a2 = red[0][2] + red[1][2] + red[2][2] + red[3][2];
        out[0] = a0 / fmaxf(a1, 1.0f) + a2;   // n2v + (0.2*wav + 0.01*tv)
    }
}

extern "C" void kernel_launch(void* const* d_in, const int* in_sizes, int n_in,
                              void* d_out, int out_size, void* d_ws, size_t ws_size,
                              hipStream_t stream) {
    (void)in_sizes; (void)n_in; (void)out_size; (void)ws_size;
    const float* pred  = (const float*)d_in[0];
    const float* noisy = (const float*)d_in[1];
    const int*   mask  = (const int*)d_in[2];

    float4* pA = (float4*)d_ws;                           // 4096 * 16 B = 64 KB

    kA<<<4096, 256, 0, stream>>>(pred, noisy, mask, pA);
    kD<<<1, 256, 0, stream>>>(pA, (float*)d_out);
}